// Round 3
// baseline (41724.207 us; speedup 1.0000x reference)
//
#include <hip/hip_runtime.h>

// Per-channel LSTM (input_size=1) + per-channel Linear(H,1), fully fused.
// B=512, T=1024, C=64, H=128.
// Round 9: compile-time phase decorrelation (fixing R8's rule-#20 bug).
//   R8 lesson: runtime rowtile index -> cndmask select chains on xv/cst
//   (VALU work 3.8ms -> 14.1ms). Rotation must be via STATIC code paths.
//   (1) Two constexpr rowtile orders {0,1,2,3} / {2,3,0,1}, selected by the
//       wave-uniform predicate ((w>>2) ^ bid) & 1, readfirstlane-pinned to
//       SGPR. Wave->SIMD is w%4: each SIMD hosts waves {s, s+4} per block,
//       which differ in (w>>2)&1 -> co-resident waves are a half-step apart,
//       so one wave's trans-heavy activation burst overlaps the other's
//       MFMA burst (R6 counters: MFMA 28% + VALU 63% + idle 9% = serial).
//   (2) R7's lean activation algebra (verified twice, same absmax).
//   (3) __launch_bounds__(512,4): force VGPR <= 128 so the dual code path
//       cannot silently drop residency to 1 block/CU.

typedef _Float16 half8 __attribute__((ext_vector_type(8)));
typedef float floatx4 __attribute__((ext_vector_type(4)));

template <int N> struct ic_t { static constexpr int value = N; };

#define LOG2E 1.44269504088896340736f

__global__ __launch_bounds__(512, 4) void lstm_fused(
    const float* __restrict__ x,    // [B,T,C]
    const float* __restrict__ Wih,  // [C,4H]
    const float* __restrict__ Whh,  // [C,4H,H]
    const float* __restrict__ bih,  // [C,4H]
    const float* __restrict__ bhh,  // [C,4H]
    const float* __restrict__ Wfc,  // [C,H]
    const float* __restrict__ bfc,  // [C]
    float* __restrict__ out)        // [B,C]
{
    constexpr int T = 1024, C = 64, H = 128, G = 512;
    constexpr int TC = T * C;

    // Two h buffers: [4 rowtiles][4 ksteps][64 chunks][8 f16] = 16 KB each.
    // TOTAL LDS = 32768 exactly — do not add a single byte (2-block residency).
    __shared__ _Float16 hbuf[2][8192];

    const int bid = blockIdx.x;
    const int ch  = bid & 63;          // channel
    const int b0  = (bid >> 6) << 6;   // batch tile base: 0,64,...,448

    const int tid = threadIdx.x;
    const int w   = tid >> 6;          // wave 0..7 -> hidden slice [w*16, w*16+16)
    const int l   = tid & 63;
    const int q   = l >> 4;            // quad
    const int li  = l & 15;
    // wave-uniform phase selector, pinned to SGPR
    const int swp = __builtin_amdgcn_readfirstlane(((w >> 2) ^ bid) & 1);

    // ---- per-lane constants: W_ih, bias, W_hh fragments in registers ----
    float wihr[4], bias[4];
    half8 Wf[4][4];
#pragma unroll
    for (int ct = 0; ct < 4; ++ct) {
        const float sc = (ct == 2) ? 2.0f * LOG2E : LOG2E;  // gate order i,f,g,o
        const int col = ct * H + w * 16 + li;
        wihr[ct] = Wih[ch * G + col] * sc;
        bias[ct] = (bih[ch * G + col] + bhh[ch * G + col]) * sc;
#pragma unroll
        for (int ks = 0; ks < 4; ++ks) {
            const float* wp = &Whh[((size_t)(ch * G + col)) * H + ks * 32 + q * 8];
            half8 hv;
#pragma unroll
            for (int j = 0; j < 8; ++j) hv[j] = (_Float16)(wp[j] * sc);
            Wf[ct][ks] = hv;
        }
    }

    // zero t=0 read buffer (h0 = 0)
    for (int i = tid; i < 8192; i += 512) hbuf[0][i] = (_Float16)0.0f;

    // cell state (fp32 registers): 4 rowtiles x 4 rows
    float cst[4][4];
#pragma unroll
    for (int rt = 0; rt < 4; ++rt)
#pragma unroll
        for (int r = 0; r < 4; ++r) cst[rt][r] = 0.0f;

    // ---- h layout with XOR bank swizzle ----
    // value (batch row m in tile, hidden hh): ks=hh>>5, qq=(hh&31)>>3, j=hh&7
    // chunk c = qq*16 + (m ^ (qq&3)); element = (rt*4+ks)*512 + c*8 + j
    const int ks_w = w >> 1;
    const int qq_w = ((w & 1) << 1) + (li >> 3);
    const int j_w  = li & 7;
    const int rxor = qq_w & 3;
    int wel[4];
#pragma unroll
    for (int r = 0; r < 4; ++r)
        wel[r] = ks_w * 512 + (qq_w * 16 + q * 4 + (r ^ rxor)) * 8 + j_w;
    // read: lane l wants chunk (qq=q, m=li) -> c = q*16 + (li ^ (q&3))
    const int rdoff = (q * 16 + (li ^ (q & 3))) * 8;

    // ---- x addressing: uniform base pointer + per-lane 32-bit offset ----
    const float* xb = x + ch;
    const int rb0 = (b0 + q * 4) * TC;  // per-lane element offset base

    float xv[4][4];
#pragma unroll
    for (int rt = 0; rt < 4; ++rt)
#pragma unroll
        for (int r = 0; r < 4; ++r)
            xv[rt][r] = xb[rb0 + (rt * 16 + r) * TC];  // t = 0

    const float* xnp   = xb + C;              // next-step base (t=1)
    const float* xlast = xb + (T - 1) * C;

    __syncthreads();

    auto step = [&](const _Float16* __restrict__ rb, _Float16* __restrict__ wb) {
        // one rowtile, rt is COMPILE-TIME (rule #20: never runtime-index
        // register arrays)
        auto do_rt = [&](auto rtc) {
            constexpr int rt = decltype(rtc)::value;

            // init acc with x*W_ih + bias (one fma each)
            floatx4 acc[4];
#pragma unroll
            for (int ct = 0; ct < 4; ++ct)
#pragma unroll
                for (int r = 0; r < 4; ++r)
                    acc[ct][r] = fmaf(xv[rt][r], wihr[ct], bias[ct]);

            // one A-fragment live at a time: ds_read_b128 then its 4 MFMAs
#pragma unroll
            for (int ks = 0; ks < 4; ++ks) {
                const half8 a = *(const half8*)&rb[(rt * 4 + ks) * 512 + rdoff];
#pragma unroll
                for (int ct = 0; ct < 4; ++ct)
                    acc[ct] = __builtin_amdgcn_mfma_f32_16x16x32_f16(a, Wf[ct][ks], acc[ct], 0, 0, 0);
            }

            // activations (preacts prescaled by log2e; g by 2*log2e):
            //   sig(i)=1/Du, sig(f)=1/Dv, tanh(g)=(p-1)/Dp, sig(o)=1/Dw
            //   c' = [c*Du*Dp + (p-1)*Dv] * rcp(Du*Dv*Dp)
            //   h' = sig(o)*tanh(c') = (e-1) * rcp(Dw*(1+e)), e=exp2(clamped)
#pragma unroll
            for (int r = 0; r < 4; ++r) {
                const float u  = __builtin_amdgcn_exp2f(-acc[0][r]);
                const float v  = __builtin_amdgcn_exp2f(-acc[1][r]);
                const float p  = __builtin_amdgcn_exp2f(acc[2][r]);
                const float wq = __builtin_amdgcn_exp2f(-acc[3][r]);
                const float Du = 1.0f + u, Dv = 1.0f + v;
                const float Dp = 1.0f + p, Dw = 1.0f + wq;
                const float DuDp = Du * Dp;
                const float R  = __builtin_amdgcn_rcpf(DuDp * Dv);
                const float cn = R * fmaf(cst[rt][r], DuDp, (p - 1.0f) * Dv);
                cst[rt][r] = cn;
                // tanh(cn): clamp exp2 arg to +-29 (tanh saturates to 1.0f)
                const float tq = __builtin_amdgcn_fmed3f(
                    cn * (2.0f * LOG2E), -29.0f, 29.0f);
                const float e  = __builtin_amdgcn_exp2f(tq);
                const float R2 = __builtin_amdgcn_rcpf(Dw * (1.0f + e));
                wb[rt * 2048 + wel[r]] = (_Float16)fmaf(e, R2, -R2);
            }
        };

        if (swp) {
            do_rt(ic_t<2>{}); do_rt(ic_t<3>{}); do_rt(ic_t<0>{}); do_rt(ic_t<1>{});
        } else {
            do_rt(ic_t<0>{}); do_rt(ic_t<1>{}); do_rt(ic_t<2>{}); do_rt(ic_t<3>{});
        }

        // reload xv for the NEXT step (same registers -> prefetch across barrier)
#pragma unroll
        for (int rt = 0; rt < 4; ++rt)
#pragma unroll
            for (int r = 0; r < 4; ++r)
                xv[rt][r] = xnp[rb0 + (rt * 16 + r) * TC];

        __syncthreads();
    };

    for (int t = 0; t < T; t += 2) {
        step(hbuf[0], hbuf[1]);
        xnp = (xnp == xlast) ? xnp : xnp + C;
        step(hbuf[1], hbuf[0]);
        xnp = (xnp == xlast) ? xnp : xnp + C;
    }

    // ---- epilogue: out[b0+row, ch] = h_final . Wfc[ch] + bfc[ch] ----
    // T even -> final h is in hbuf[0]; last __syncthreads already done.
    if (tid < 64) {
        const int row = tid;
        const int rt = row >> 4, m = row & 15;
        float s = bfc[ch];
#pragma unroll
        for (int hh = 0; hh < H; ++hh) {
            const int ks = hh >> 5, qq = (hh & 31) >> 3, j = hh & 7;
            const int c = qq * 16 + (m ^ (qq & 3));
            s += (float)hbuf[0][(rt * 4 + ks) * 512 + c * 8 + j] * Wfc[ch * H + hh];
        }
        out[(size_t)(b0 + row) * C + ch] = s;
    }
}

extern "C" void kernel_launch(void* const* d_in, const int* in_sizes, int n_in,
                              void* d_out, int out_size, void* d_ws, size_t ws_size,
                              hipStream_t stream) {
    const float* x   = (const float*)d_in[0];
    const float* Wih = (const float*)d_in[1];
    const float* Whh = (const float*)d_in[2];
    const float* bih = (const float*)d_in[3];
    const float* bhh = (const float*)d_in[4];
    const float* Wfc = (const float*)d_in[5];
    const float* bfc = (const float*)d_in[6];
    float* out = (float*)d_out;

    lstm_fused<<<512, 512, 0, stream>>>(x, Wih, Whh, bih, bhh, Wfc, bfc, out);
}

// Round 4
// 9712.428 us; speedup vs baseline: 4.2960x; 4.2960x over previous
//
#include <hip/hip_runtime.h>

// Per-channel LSTM (input_size=1) + per-channel Linear(H,1), fully fused.
// B=512, T=1024, C=64, H=128.
// Round 10: phase decorrelation via DATA permutation (R8/R9 post-mortems).
//   R8 failed: runtime register-array index -> cndmask chains (3.7x VALU).
//   R9 failed: static code duplication -> live-range blowup -> spills.
//   Fix: loop stays EXACTLY R6-shaped (compile-time rt for xv/cst), but the
//   physical rowtile each rt maps to is rotated per wave through WAVE-UNIFORM
//   SGPR offset tables into LDS and x addresses only:
//     srot[rt] = ((rt+rp)&3)*2048 (LDS elems), sxo[rt] = ((rt+rp)&3)*16*TC.
//     rp = ((w>>2) + (bid&1)*2) & 3, readfirstlane-pinned.
//   cst[rt]/xv[rt] hold physical rowtile (rt+rp)&3 state for the whole kernel
//   (rp is constant), so correctness is a pure relabeling. Cost: ~24 v_add
//   (sgpr+vgpr) per step, ZERO extra VGPRs, zero duplicated code.
//   Mechanism: co-resident waves on a SIMD ({w,w+4} x 2 blocks) process
//   rowtiles in staggered order -> one wave's MFMA burst overlaps another's
//   trans-heavy activation burst (R6: both pipes serialized in lockstep).
//   Registers: MUST stay at launch_bounds(512,2), ~116 VGPR; residency
//   cliff at 128 total regs/wave (R7/R9 evidence). LDS must stay 32768.

typedef _Float16 half8 __attribute__((ext_vector_type(8)));
typedef float floatx4 __attribute__((ext_vector_type(4)));

#define LOG2E 1.44269504088896340736f

__global__ __launch_bounds__(512, 2) void lstm_fused(
    const float* __restrict__ x,    // [B,T,C]
    const float* __restrict__ Wih,  // [C,4H]
    const float* __restrict__ Whh,  // [C,4H,H]
    const float* __restrict__ bih,  // [C,4H]
    const float* __restrict__ bhh,  // [C,4H]
    const float* __restrict__ Wfc,  // [C,H]
    const float* __restrict__ bfc,  // [C]
    float* __restrict__ out)        // [B,C]
{
    constexpr int T = 1024, C = 64, H = 128, G = 512;
    constexpr int TC = T * C;

    // Two h buffers: [4 rowtiles][4 ksteps][64 chunks][8 f16] = 16 KB each.
    // TOTAL LDS = 32768 exactly — do not add a single byte (2-block residency).
    __shared__ _Float16 hbuf[2][8192];

    const int bid = blockIdx.x;
    const int ch  = bid & 63;          // channel
    const int b0  = (bid >> 6) << 6;   // batch tile base: 0,64,...,448

    const int tid = threadIdx.x;
    const int w   = tid >> 6;          // wave 0..7 -> hidden slice [w*16, w*16+16)
    const int l   = tid & 63;
    const int q   = l >> 4;            // quad
    const int li  = l & 15;

    // ---- wave-uniform rowtile rotation tables (SGPR-pinned) ----
    // rp: waves {s,s+4} of a block differ in (w>>2); two co-scheduled blocks
    // differ in (bid&1) -> co-resident SIMD waves span phases {0,1,2,3}
    // (worst case {0,1}x2). Pure relabeling of which physical rowtile the
    // compile-time index rt refers to.
    const int rp = __builtin_amdgcn_readfirstlane(((tid >> 8) + ((bid & 1) << 1)) & 3);
    int srot[4], sxo[4];
#pragma unroll
    for (int rt = 0; rt < 4; ++rt) {
        const int prt = (rt + rp) & 3;
        srot[rt] = __builtin_amdgcn_readfirstlane(prt * 2048);      // LDS elems
        sxo[rt]  = __builtin_amdgcn_readfirstlane(prt * 16 * TC);   // x elems
    }

    // ---- per-lane constants: W_ih, bias, W_hh fragments in registers ----
    float wihr[4], bias[4];
    half8 Wf[4][4];
#pragma unroll
    for (int ct = 0; ct < 4; ++ct) {
        const float sc = (ct == 2) ? 2.0f * LOG2E : LOG2E;  // gate order i,f,g,o
        const int col = ct * H + w * 16 + li;
        wihr[ct] = Wih[ch * G + col] * sc;
        bias[ct] = (bih[ch * G + col] + bhh[ch * G + col]) * sc;
#pragma unroll
        for (int ks = 0; ks < 4; ++ks) {
            const float* wp = &Whh[((size_t)(ch * G + col)) * H + ks * 32 + q * 8];
            half8 hv;
#pragma unroll
            for (int j = 0; j < 8; ++j) hv[j] = (_Float16)(wp[j] * sc);
            Wf[ct][ks] = hv;
        }
    }

    // zero t=0 read buffer (h0 = 0)
    for (int i = tid; i < 8192; i += 512) hbuf[0][i] = (_Float16)0.0f;

    // cell state (fp32 registers): cst[rt] holds PHYSICAL rowtile (rt+rp)&3
    float cst[4][4];
#pragma unroll
    for (int rt = 0; rt < 4; ++rt)
#pragma unroll
        for (int r = 0; r < 4; ++r) cst[rt][r] = 0.0f;

    // ---- h layout with XOR bank swizzle (physical layout unchanged) ----
    // value (batch row m in tile, hidden hh): ks=hh>>5, qq=(hh&31)>>3, j=hh&7
    // chunk c = qq*16 + (m ^ (qq&3)); element = prt*2048 + ks*512 + c*8 + j
    const int ks_w = w >> 1;
    const int qq_w = ((w & 1) << 1) + (li >> 3);
    const int j_w  = li & 7;
    const int rxor = qq_w & 3;
    int wel[4];
#pragma unroll
    for (int r = 0; r < 4; ++r)
        wel[r] = ks_w * 512 + (qq_w * 16 + q * 4 + (r ^ rxor)) * 8 + j_w;
    // read: lane l wants chunk (qq=q, m=li) -> c = q*16 + (li ^ (q&3))
    const int rdoff = (q * 16 + (li ^ (q & 3))) * 8;

    // ---- x addressing: uniform base pointer + per-lane 32-bit offset ----
    const float* xb = x + ch;
    const int rb0 = (b0 + q * 4) * TC;  // per-lane element offset base

    float xv[4][4];                     // xv[rt] holds PHYSICAL rowtile (rt+rp)&3
#pragma unroll
    for (int rt = 0; rt < 4; ++rt)
#pragma unroll
        for (int r = 0; r < 4; ++r)
            xv[rt][r] = xb[rb0 + sxo[rt] + r * TC];  // t = 0

    const float* xnp   = xb + C;              // next-step base (t=1)
    const float* xlast = xb + (T - 1) * C;

    __syncthreads();

    auto step = [&](const _Float16* __restrict__ rb, _Float16* __restrict__ wb) {
#pragma unroll
        for (int rt = 0; rt < 4; ++rt) {
            // init acc with x*W_ih + bias (one fma each)
            floatx4 acc[4];
#pragma unroll
            for (int ct = 0; ct < 4; ++ct)
#pragma unroll
                for (int r = 0; r < 4; ++r)
                    acc[ct][r] = fmaf(xv[rt][r], wihr[ct], bias[ct]);

            // one A-fragment live at a time: ds_read_b128 then its 4 MFMAs
#pragma unroll
            for (int ks = 0; ks < 4; ++ks) {
                const half8 a = *(const half8*)&rb[srot[rt] + ks * 512 + rdoff];
#pragma unroll
                for (int ct = 0; ct < 4; ++ct)
                    acc[ct] = __builtin_amdgcn_mfma_f32_16x16x32_f16(a, Wf[ct][ks], acc[ct], 0, 0, 0);
            }

            // activations (preacts prescaled by log2e; g by 2*log2e):
            //   sig(i)=1/Du, sig(f)=1/Dv, tanh(g)=(p-1)/Dp, sig(o)=1/Dw
            //   c' = [c*Du*Dp + (p-1)*Dv] * rcp(Du*Dv*Dp)
            //   h' = sig(o)*tanh(c') = (e-1) * rcp(Dw*(1+e)), e=exp2(clamped)
#pragma unroll
            for (int r = 0; r < 4; ++r) {
                const float u  = __builtin_amdgcn_exp2f(-acc[0][r]);
                const float v  = __builtin_amdgcn_exp2f(-acc[1][r]);
                const float p  = __builtin_amdgcn_exp2f(acc[2][r]);
                const float wq = __builtin_amdgcn_exp2f(-acc[3][r]);
                const float Du = 1.0f + u, Dv = 1.0f + v;
                const float Dp = 1.0f + p, Dw = 1.0f + wq;
                const float DuDp = Du * Dp;
                const float R  = __builtin_amdgcn_rcpf(DuDp * Dv);
                const float cn = R * fmaf(cst[rt][r], DuDp, (p - 1.0f) * Dv);
                cst[rt][r] = cn;
                // tanh(cn): clamp exp2 arg to +-29 (tanh saturates to 1.0f)
                const float tq = __builtin_amdgcn_fmed3f(
                    cn * (2.0f * LOG2E), -29.0f, 29.0f);
                const float e  = __builtin_amdgcn_exp2f(tq);
                const float R2 = __builtin_amdgcn_rcpf(Dw * (1.0f + e));
                wb[srot[rt] + wel[r]] = (_Float16)fmaf(e, R2, -R2);
            }
        }

        // reload xv for the NEXT step (same registers -> prefetch across barrier)
#pragma unroll
        for (int rt = 0; rt < 4; ++rt)
#pragma unroll
            for (int r = 0; r < 4; ++r)
                xv[rt][r] = xnp[rb0 + sxo[rt] + r * TC];

        __syncthreads();
    };

    for (int t = 0; t < T; t += 2) {
        step(hbuf[0], hbuf[1]);
        xnp = (xnp == xlast) ? xnp : xnp + C;
        step(hbuf[1], hbuf[0]);
        xnp = (xnp == xlast) ? xnp : xnp + C;
    }

    // ---- epilogue: out[b0+row, ch] = h_final . Wfc[ch] + bfc[ch] ----
    // T even -> final h is in hbuf[0]; last __syncthreads already done.
    // Physical layout in LDS is rotation-independent.
    if (tid < 64) {
        const int row = tid;
        const int rt = row >> 4, m = row & 15;
        float s = bfc[ch];
#pragma unroll
        for (int hh = 0; hh < H; ++hh) {
            const int ks = hh >> 5, qq = (hh & 31) >> 3, j = hh & 7;
            const int c = qq * 16 + (m ^ (qq & 3));
            s += (float)hbuf[0][(rt * 4 + ks) * 512 + c * 8 + j] * Wfc[ch * H + hh];
        }
        out[(size_t)(b0 + row) * C + ch] = s;
    }
}

extern "C" void kernel_launch(void* const* d_in, const int* in_sizes, int n_in,
                              void* d_out, int out_size, void* d_ws, size_t ws_size,
                              hipStream_t stream) {
    const float* x   = (const float*)d_in[0];
    const float* Wih = (const float*)d_in[1];
    const float* Whh = (const float*)d_in[2];
    const float* bih = (const float*)d_in[3];
    const float* bhh = (const float*)d_in[4];
    const float* Wfc = (const float*)d_in[5];
    const float* bfc = (const float*)d_in[6];
    float* out = (float*)d_out;

    lstm_fused<<<512, 512, 0, stream>>>(x, Wih, Whh, bih, bhh, Wfc, bfc, out);
}

// Round 5
// 5503.648 us; speedup vs baseline: 7.5812x; 1.7647x over previous
//
#include <hip/hip_runtime.h>

// Per-channel LSTM (input_size=1) + per-channel Linear(H,1), fully fused.
// B=512, T=1024, C=64, H=128.
// Round 11: within-wave MFMA/VALU software pipelining (double-buffered acc).
//   R6 budget closure: wall 14200 cyc/step = VALU 8950 + MFMA 3980 + idle;
//   pipes STRICTLY serial because one acc buffer forces act(rt) to directly
//   consume MFMA(rt); no registers were spare to rename a second (116/128).
//   R7/R9/R10 lessons: 128-VGPR granule cliff, compiler spills rather than
//   cross it; every failed round was a register side-effect, not the idea.
//   This round: accA/accB (+16), and pay for it:
//     -8: persistent xv[4][4] -> two 4-reg x buffers (xE/xO), each loaded
//         one full phase before use (latency 900cyc < phase ~2500cyc);
//     -4: wihr/bias packed to f16 pairs (wbp), cvt at use (fma_mix-able);
//     -3: wel[4] -> single base K2, per-write addr = K2 ^ (r*8). Valid since
//         chunk bits are disjoint: (r^rxor) occupies element bits 3-4 only.
//   Schedule per step (one barrier, same as R6):
//     PRO: mfma(0,A,xE); load xE<-x(t,rt2)
//     P0 : mfma(1,B,xO); load xO<-x(t,rt3); act(0,A)
//     P1 : mfma(2,A,xE); load xE<-x(t+1,rt0); act(1,B)
//     P2 : mfma(3,B,xO); load xO<-x(t+1,rt1); act(2,A)
//     P3 : act(3,B); barrier
//   MFMA(rt+1) has no consumer until next phase -> scheduler interleaves it
//   into act(rt)'s trans burst; MFMA 3980cyc hides under VALU 8950cyc.
//   TRIPWIRES: VGPR must stay <=126 and WRITE_SIZE ~1KB (else spilled).

typedef _Float16 half8  __attribute__((ext_vector_type(8)));
typedef _Float16 half2v __attribute__((ext_vector_type(2)));
typedef float    floatx4 __attribute__((ext_vector_type(4)));

template <int N> struct ic_t { static constexpr int value = N; };

#define LOG2E 1.44269504088896340736f

__global__ __launch_bounds__(512, 2) void lstm_fused(
    const float* __restrict__ x,    // [B,T,C]
    const float* __restrict__ Wih,  // [C,4H]
    const float* __restrict__ Whh,  // [C,4H,H]
    const float* __restrict__ bih,  // [C,4H]
    const float* __restrict__ bhh,  // [C,4H]
    const float* __restrict__ Wfc,  // [C,H]
    const float* __restrict__ bfc,  // [C]
    float* __restrict__ out)        // [B,C]
{
    constexpr int T = 1024, C = 64, H = 128, G = 512;
    constexpr int TC = T * C;

    // Two h buffers: [4 rowtiles][4 ksteps][64 chunks][8 f16] = 16 KB each.
    // TOTAL LDS = 32768 exactly — do not add a single byte (2-block residency).
    __shared__ _Float16 hbuf[2][8192];

    const int bid = blockIdx.x;
    const int ch  = bid & 63;          // channel
    const int b0  = (bid >> 6) << 6;   // batch tile base: 0,64,...,448

    const int tid = threadIdx.x;
    const int w   = tid >> 6;          // wave 0..7 -> hidden slice [w*16, w*16+16)
    const int l   = tid & 63;
    const int q   = l >> 4;            // quad
    const int li  = l & 15;

    // ---- x addressing: uniform base pointer + per-lane 32-bit offset ----
    const float* xb = x + ch;
    const int rb0 = (b0 + q * 4) * TC;  // per-lane element offset base

    // x staging: two 4-reg buffers, each consumed one full phase after load.
    float xE[4], xO[4];
#pragma unroll
    for (int r = 0; r < 4; ++r) xE[r] = xb[rb0 + r * TC];          // t=0, rt0
#pragma unroll
    for (int r = 0; r < 4; ++r) xO[r] = xb[rb0 + (16 + r) * TC];   // t=0, rt1

    // ---- per-lane constants: packed W_ih+bias (f16), W_hh fragments ----
    half2v wbp[4];
    half8 Wf[4][4];
#pragma unroll
    for (int ct = 0; ct < 4; ++ct) {
        const float sc = (ct == 2) ? 2.0f * LOG2E : LOG2E;  // gate order i,f,g,o
        const int col = ct * H + w * 16 + li;
        wbp[ct][0] = (_Float16)(Wih[ch * G + col] * sc);
        wbp[ct][1] = (_Float16)((bih[ch * G + col] + bhh[ch * G + col]) * sc);
#pragma unroll
        for (int ks = 0; ks < 4; ++ks) {
            const float* wp = &Whh[((size_t)(ch * G + col)) * H + ks * 32 + q * 8];
            half8 hv;
#pragma unroll
            for (int j = 0; j < 8; ++j) hv[j] = (_Float16)(wp[j] * sc);
            Wf[ct][ks] = hv;
        }
    }

    // zero t=0 read buffer (h0 = 0)
    for (int i = tid; i < 8192; i += 512) hbuf[0][i] = (_Float16)0.0f;

    // cell state (fp32 registers): 4 rowtiles x 4 rows
    float cst[4][4];
#pragma unroll
    for (int rt = 0; rt < 4; ++rt)
#pragma unroll
        for (int r = 0; r < 4; ++r) cst[rt][r] = 0.0f;

    // ---- h layout with XOR bank swizzle ----
    // value (batch row m in tile, hidden hh): ks=hh>>5, qq=(hh&31)>>3, j=hh&7
    // chunk c = qq*16 + (m ^ (qq&3)); element = (rt*4+ks)*512 + c*8 + j
    const int ks_w = w >> 1;
    const int qq_w = ((w & 1) << 1) + (li >> 3);
    const int j_w  = li & 7;
    const int rxor = qq_w & 3;
    // write base: bits of (qq_w*16 + q*4), (r^rxor), ks_w*512, j_w are
    // disjoint -> addr(r) = K2 ^ (r*8), K2 = base ^ (rxor<<3).
    const int K2 = (ks_w * 512 + (qq_w * 16 + q * 4) * 8 + j_w) ^ (rxor << 3);
    // read: lane l wants chunk (qq=q, m=li) -> c = q*16 + (li ^ (q&3))
    const int rdoff = (q * 16 + (li ^ (q & 3))) * 8;

    __syncthreads();

    // ---- phase building blocks (rt strictly compile-time) ----
    auto mfma_rt = [&](auto rtc, floatx4 (&acc)[4], const _Float16* __restrict__ rb,
                       const float (&xq)[4]) {
        constexpr int rt = decltype(rtc)::value;
#pragma unroll
        for (int ct = 0; ct < 4; ++ct) {
            const float wi = (float)wbp[ct][0];
            const float bb = (float)wbp[ct][1];
#pragma unroll
            for (int r = 0; r < 4; ++r)
                acc[ct][r] = fmaf(xq[r], wi, bb);
        }
#pragma unroll
        for (int ks = 0; ks < 4; ++ks) {
            const half8 a = *(const half8*)&rb[(rt * 4 + ks) * 512 + rdoff];
#pragma unroll
            for (int ct = 0; ct < 4; ++ct)
                acc[ct] = __builtin_amdgcn_mfma_f32_16x16x32_f16(a, Wf[ct][ks], acc[ct], 0, 0, 0);
        }
    };

    auto act_rt = [&](auto rtc, floatx4 (&acc)[4], _Float16* __restrict__ wb) {
        constexpr int rt = decltype(rtc)::value;
        // activations (preacts prescaled by log2e; g by 2*log2e):
        //   sig(i)=1/Du, sig(f)=1/Dv, tanh(g)=(p-1)/Dp, sig(o)=1/Dw
        //   c' = [c*Du*Dp + (p-1)*Dv] * rcp(Du*Dv*Dp)
        //   h' = sig(o)*tanh(c') = (e-1) * rcp(Dw*(1+e)), e=exp2(clamped)
#pragma unroll
        for (int r = 0; r < 4; ++r) {
            const float u  = __builtin_amdgcn_exp2f(-acc[0][r]);
            const float v  = __builtin_amdgcn_exp2f(-acc[1][r]);
            const float p  = __builtin_amdgcn_exp2f(acc[2][r]);
            const float wq = __builtin_amdgcn_exp2f(-acc[3][r]);
            const float Du = 1.0f + u, Dv = 1.0f + v;
            const float Dp = 1.0f + p, Dw = 1.0f + wq;
            const float DuDp = Du * Dp;
            const float R  = __builtin_amdgcn_rcpf(DuDp * Dv);
            const float cn = R * fmaf(cst[rt][r], DuDp, (p - 1.0f) * Dv);
            cst[rt][r] = cn;
            // tanh(cn): clamp exp2 arg to +-29 (tanh saturates to 1.0f)
            const float tq = __builtin_amdgcn_fmed3f(
                cn * (2.0f * LOG2E), -29.0f, 29.0f);
            const float e  = __builtin_amdgcn_exp2f(tq);
            const float R2 = __builtin_amdgcn_rcpf(Dw * (1.0f + e));
            wb[rt * 2048 + (K2 ^ (r * 8))] = (_Float16)fmaf(e, R2, -R2);
        }
    };

    auto load_x = [&](float (&xq)[4], const float* base, int off) {
#pragma unroll
        for (int r = 0; r < 4; ++r) xq[r] = base[rb0 + off + r * TC];
    };

    auto step = [&](const _Float16* __restrict__ rb, _Float16* __restrict__ wb,
                    const float* xt, const float* xtn) {
        floatx4 accA[4], accB[4];
        // PRO
        mfma_rt(ic_t<0>{}, accA, rb, xE);
        load_x(xE, xt, 32 * TC);            // x(t, rt2)
        // P0
        mfma_rt(ic_t<1>{}, accB, rb, xO);
        load_x(xO, xt, 48 * TC);            // x(t, rt3)
        act_rt(ic_t<0>{}, accA, wb);
        // P1
        mfma_rt(ic_t<2>{}, accA, rb, xE);
        load_x(xE, xtn, 0);                 // x(t+1, rt0)
        act_rt(ic_t<1>{}, accB, wb);
        // P2
        mfma_rt(ic_t<3>{}, accB, rb, xO);
        load_x(xO, xtn, 16 * TC);           // x(t+1, rt1)
        act_rt(ic_t<2>{}, accA, wb);
        // P3
        act_rt(ic_t<3>{}, accB, wb);
        __syncthreads();
    };

    const float* xt = xb;
    for (int t = 0; t < T; t += 2) {
        const float* x1 = xt + C;                       // t+1 (t <= T-2)
        const float* x2 = (t + 2 < T) ? x1 + C : x1;    // t+2, clamped in-bounds
        step(hbuf[0], hbuf[1], xt, x1);
        step(hbuf[1], hbuf[0], x1, x2);
        xt = x2;
    }

    // ---- epilogue: out[b0+row, ch] = h_final . Wfc[ch] + bfc[ch] ----
    // T even -> final h is in hbuf[0]; last __syncthreads already done.
    if (tid < 64) {
        const int row = tid;
        const int rt = row >> 4, m = row & 15;
        float s = bfc[ch];
#pragma unroll
        for (int hh = 0; hh < H; ++hh) {
            const int ks = hh >> 5, qq = (hh & 31) >> 3, j = hh & 7;
            const int c = qq * 16 + (m ^ (qq & 3));
            s += (float)hbuf[0][(rt * 4 + ks) * 512 + c * 8 + j] * Wfc[ch * H + hh];
        }
        out[(size_t)(b0 + row) * C + ch] = s;
    }
}

extern "C" void kernel_launch(void* const* d_in, const int* in_sizes, int n_in,
                              void* d_out, int out_size, void* d_ws, size_t ws_size,
                              hipStream_t stream) {
    const float* x   = (const float*)d_in[0];
    const float* Wih = (const float*)d_in[1];
    const float* Whh = (const float*)d_in[2];
    const float* bih = (const float*)d_in[3];
    const float* bhh = (const float*)d_in[4];
    const float* Wfc = (const float*)d_in[5];
    const float* bfc = (const float*)d_in[6];
    float* out = (float*)d_out;

    lstm_fused<<<512, 512, 0, stream>>>(x, Wih, Whh, bih, bhh, Wfc, bfc, out);
}